// Round 11
// baseline (1223.679 us; speedup 1.0000x reference)
//
#include <hip/hip_runtime.h>
#include <math.h>

#define BB 4
#define N0 4096
#define NEWP 1152
#define GD 256
#define HD 128
#define KSEL 64
#define NSTEPS 10
#define NMAX (N0 + NSTEPS*NEWP)   /* 15616 */
#define NNEW (NSTEPS*NEWP)        /* 11520 */
#define F2S (BB*N0)               /* 16384: stride of f2buf[k][b*N0+i] */

/* ---- workspace layout (float offsets) ---- */
#define OFF_CANVAS 0
#define OFF_MINAB  (OFF_CANVAS + BB*NMAX*3)
#define OFF_MINCD  (OFF_MINAB + 2*BB*N0)
#define OFF_GMAX   (OFF_MINCD + BB*NNEW + BB*N0)
#define OFF_H      (OFF_GMAX + BB*GD)          /* 2 buffers */
#define OFF_C      (OFF_H + 2*BB*HD)           /* 2 buffers */
#define OFF_ACC    (OFF_C + 2*BB*HD)
#define OFF_CENTER (OFF_ACC + 16)
#define OFF_PART   (OFF_CENTER + 32)           /* BB*32*8 */
#define OFF_GPART  (OFF_PART + BB*32*8)        /* 32*BB*512 */
#define OFF_F2     (OFF_GPART + 32*BB*512)     /* 128*F2S */
#define WS_FLOATS  (OFF_F2 + 128*F2S)

__device__ __forceinline__ unsigned enc_f(float f){
  unsigned u = __float_as_uint(f);
  return (u & 0x80000000u) ? ~u : (u | 0x80000000u);
}
__device__ __forceinline__ float dec_f(unsigned e){
  unsigned u = (e & 0x80000000u) ? (e & 0x7fffffffu) : ~e;
  return __uint_as_float(u);
}
__device__ __forceinline__ float sigm(float x){ return 1.f/(1.f+expf(-x)); }

__device__ __forceinline__ float block_sum(float v, volatile float* red){
#pragma unroll
  for (int s=32;s>0;s>>=1) v += __shfl_down(v, s, 64);
  int lane = threadIdx.x & 63, w = threadIdx.x >> 6, nw = blockDim.x >> 6;
  __syncthreads();
  if (lane==0) red[w] = v;
  __syncthreads();
  if (w==0){
    float x = (lane < nw) ? red[lane] : 0.f;
#pragma unroll
    for (int s=8;s>0;s>>=1) x += __shfl_down(x, s, 64);
    if (lane==0) red[0] = x;
  }
  __syncthreads();
  float r = red[0];
  __syncthreads();
  return r;
}
__device__ __forceinline__ float block_max(float v, volatile float* red){
#pragma unroll
  for (int s=32;s>0;s>>=1) v = fmaxf(v, __shfl_down(v, s, 64));
  int lane = threadIdx.x & 63, w = threadIdx.x >> 6, nw = blockDim.x >> 6;
  __syncthreads();
  if (lane==0) red[w] = v;
  __syncthreads();
  if (w==0){
    float x = (lane < nw) ? red[lane] : -3.4e38f;
#pragma unroll
    for (int s=8;s>0;s>>=1) x = fmaxf(x, __shfl_down(x, s, 64));
    if (lane==0) red[0] = x;
  }
  __syncthreads();
  float r = red[0];
  __syncthreads();
  return r;
}

/* ---------- init ---------- */
__global__ __launch_bounds__(512) void init_kernel(
    const float* __restrict__ points,
    float* __restrict__ canvas, unsigned* __restrict__ minAB,
    unsigned* __restrict__ minCD, unsigned* __restrict__ gmax,
    float* __restrict__ h, float* __restrict__ c)
{
  int gid = blockIdx.x*512 + threadIdx.x;
  if (gid < BB*N0*3){
    int b = gid/(N0*3), r = gid - b*(N0*3);
    canvas[(size_t)b*NMAX*3 + r] = points[gid];
  }
  if (gid < 2*BB*N0) minAB[gid] = 0xFFFFFFFFu;
  if (gid < BB*NNEW + BB*N0) minCD[gid] = 0xFFFFFFFFu;
  if (gid < BB*GD) gmax[gid] = 0u;
  if (gid < 2*BB*HD){ h[gid]=0.f; c[gid]=0.f; }
}

/* ---------- enc layers 1+2 (standalone, t=0 only) ---------- */
__global__ __launch_bounds__(256) void enc12_kernel(
    const float* __restrict__ canvas, const float* __restrict__ w1,
    const float* __restrict__ b1, const float* __restrict__ w2,
    const float* __restrict__ b2, float* __restrict__ f2buf,
    int off, int M)
{
  int b = blockIdx.y;
  int jc = blockIdx.z;            /* 0..7 */
  int i = blockIdx.x*256 + threadIdx.x;
  int ii = (i < M) ? i : 0;
  const float* p = canvas + (size_t)(b*NMAX + off + ii)*3;
  float p0 = p[0], p1 = p[1], p2 = p[2];
  float f1[64];
#pragma unroll
  for (int j=0;j<64;j++)
    f1[j] = fmaxf(0.f, b1[j] + p0*w1[j] + p1*w1[64+j] + p2*w1[128+j]);
  float a[16];
  const float* b2p = b2 + jc*16;
#pragma unroll
  for (int j=0;j<16;j++) a[j] = b2p[j];
#pragma unroll
  for (int k=0;k<64;k++){
    const float* wr = w2 + k*128 + jc*16;   /* wave-uniform -> scalar */
#pragma unroll
    for (int j=0;j<16;j++) a[j] = fmaf(f1[k], wr[j], a[j]);
  }
  if (i < M){
    int base = b*N0 + i;
#pragma unroll
    for (int j=0;j<16;j++)
      f2buf[(size_t)(jc*16 + j)*F2S + base] = fmaxf(a[j], 0.f);
  }
}

/* ---------- enc layer 3 + running max-pool ---------- */
__global__ __launch_bounds__(256) void enc3_kernel(
    const float* __restrict__ f2buf, const float* __restrict__ w3,
    const float* __restrict__ b3, unsigned* __restrict__ gmax, int M)
{
  int b = blockIdx.y;
  int dc = blockIdx.z;            /* 0..15 */
  int i = blockIdx.x*256 + threadIdx.x;
  bool act = i < M;
  int ii = act ? i : 0;
  const float* fp = f2buf + b*N0 + ii;
  float a[16];
  const float* b3p = b3 + dc*16;
#pragma unroll
  for (int d=0;d<16;d++) a[d] = b3p[d];
  for (int k=0;k<128;k++){
    float fk = fp[(size_t)k*F2S];           /* coalesced */
    const float* wr = w3 + k*256 + dc*16;   /* wave-uniform -> scalar */
#pragma unroll
    for (int d=0;d<16;d++) a[d] = fmaf(fk, wr[d], a[d]);
  }
#pragma unroll
  for (int d=0;d<16;d++){
    float v = act ? a[d] : -3.4e38f;
#pragma unroll
    for (int s=32;s>0;s>>=1) v = fmaxf(v, __shfl_down(v, s, 64));
    if ((threadIdx.x & 63) == 0) atomicMax(&gmax[b*GD + dc*16 + d], enc_f(v));
  }
}

/* ---------- scores partials + lstm partials, one dispatch ---------- */
__global__ __launch_bounds__(512) void sl_kernel(
    const float* __restrict__ canvas, const float* __restrict__ aw1,
    const float* __restrict__ ab1, const float* __restrict__ aw2,
    const float* __restrict__ ab2, const unsigned* __restrict__ gmax,
    const float* __restrict__ h_in,
    const float* __restrict__ wih, const float* __restrict__ whh,
    float* __restrict__ part, float* __restrict__ gpart, int N, int nch)
{
  __shared__ float sBatt[128];
  __shared__ float red[16];
  __shared__ float sV[BB][12];
  int blk = blockIdx.x;
  int tid = threadIdx.x;
  if (blk < 4*nch){
    int b = blk / nch, ch = blk - b*nch;
    if (tid < 128){
      float a = ab1[tid];
      for (int k=0;k<GD;k++) a += dec_f(gmax[b*GD+k]) * aw1[(3+k)*128 + tid];
      for (int k=0;k<HD;k++) a += h_in[b*HD+k] * aw1[(3+GD+k)*128 + tid];
      sBatt[tid] = a;
    }
    __syncthreads();
    int i = ch*512 + tid;
    bool act = i < N;
    float p0=0.f,p1=0.f,p2=0.f,s=-3.4e38f;
    if (act){
      const float* pp = canvas + (size_t)(b*NMAX + i)*3;
      p0=pp[0]; p1=pp[1]; p2=pp[2];
      s = ab2[0];
      for (int j=0;j<128;j++){
        float v = sBatt[j] + p0*aw1[j] + p1*aw1[128+j] + p2*aw1[256+j];
        s += fmaxf(v, 0.f)*aw2[j];
      }
    }
    float mb = block_max(s, red);
    float e = act ? expf(s - mb) : 0.f;
    float se = block_sum(e, red);
    float wx = block_sum(e*p0, red);
    float wy = block_sum(e*p1, red);
    float wz = block_sum(e*p2, red);
    if (tid==0){
      float* pr = part + (size_t)(b*32 + ch)*8;
      pr[0]=mb; pr[1]=se; pr[2]=wx; pr[3]=wy; pr[4]=wz;
    }
  } else {
    int cc = blk - 4*nch;   /* 0..31 */
    if (tid < BB*12){
      int b = tid/12, j = tid - b*12;
      int r = cc*12 + j;
      sV[b][j] = (r < 256) ? dec_f(gmax[b*GD + r]) : h_in[b*HD + (r-256)];
    }
    __syncthreads();
    float a0=0.f,a1=0.f,a2=0.f,a3=0.f;
#pragma unroll
    for (int j=0;j<12;j++){
      int r = cc*12 + j;
      const float* wr = (r < 256) ? (wih + (size_t)r*512) : (whh + (size_t)(r-256)*512);
      float wvv = wr[tid];
      a0 += sV[0][j]*wvv; a1 += sV[1][j]*wvv;
      a2 += sV[2][j]*wvv; a3 += sV[3][j]*wvv;
    }
    float* gp = gpart + (size_t)cc*(BB*512);
    gp[0*512+tid]=a0; gp[1*512+tid]=a1; gp[2*512+tid]=a2; gp[3*512+tid]=a3;
  }
}

/* ---------- stepA: center + top-64 threshold + patch mean ---------- */
__global__ __launch_bounds__(1024) void stepA_kernel(
    const float* __restrict__ canvas, const float* __restrict__ part,
    float* __restrict__ centerpf, int N, int nch)
{
  __shared__ float red[16];
  __shared__ float sC[3];
  __shared__ unsigned cbufA[2][16];
  __shared__ unsigned cbufB[2][16];
  __shared__ int tieCnt;
  __shared__ int tieIdx[256];

  int b = blockIdx.x;
  int tid = threadIdx.x;
  int lane = tid & 63, wid = tid >> 6;
  const float* cv = canvas + (size_t)b*NMAX*3;

  float pm=-3.4e38f, pse=0.f, pwx=0.f, pwy=0.f, pwz=0.f;
  if (tid < nch){
    const float* pp = part + (size_t)(b*32 + tid)*8;
    pm=pp[0]; pse=pp[1]; pwx=pp[2]; pwy=pp[3]; pwz=pp[4];
  }
  float M = block_max(pm, red);
  float w = (tid < nch) ? expf(pm - M) : 0.f;
  float se = block_sum(pse*w, red);
  float wx = block_sum(pwx*w, red);
  float wy = block_sum(pwy*w, red);
  float wz = block_sum(pwz*w, red);
  if (tid==0){ sC[0]=wx/se; sC[1]=wy/se; sC[2]=wz/se; }
  __syncthreads();
  float cx=sC[0], cy=sC[1], cz=sC[2];
  if (tid<3) centerpf[b*3+tid] = sC[tid];

  unsigned ur[16];
#pragma unroll
  for (int q=0;q<16;q++){
    ur[q] = 0xFFFFFFFFu;
    int i = tid + q*1024;
    if (i < N){
      const float* p = cv + (size_t)i*3;
      float dx=p[0]-cx, dy=p[1]-cy, dz=p[2]-cz;
      ur[q] = __float_as_uint(dx*dx + dy*dy + dz*dz);
    }
  }

  unsigned T = 0u;
  int cntBelow = 0;
  int par = 0;
  {
    unsigned cand = 1u<<30;
    unsigned tc = 0;
#pragma unroll
    for (int q=0;q<16;q++) tc += (ur[q] < cand) ? 1u : 0u;
#pragma unroll
    for (int s=32;s>0;s>>=1) tc += __shfl_down(tc, s, 64);
    if (lane==0) cbufA[par][wid] = tc;
    __syncthreads();
    unsigned tot = 0;
#pragma unroll
    for (int i2=0;i2<16;i2++) tot += cbufA[par][i2];
    if ((int)tot < KSEL){ T = cand; cntBelow = (int)tot; }
    par ^= 1;
  }
  for (int bit=29; bit>=1; bit-=2){
    unsigned q1 = 1u<<(bit-1);
    unsigned c1 = T + q1, c2 = T + 2u*q1, c3 = T + 3u*q1;
    unsigned ta = 0, tb = 0;
#pragma unroll
    for (int q=0;q<16;q++){
      unsigned u = ur[q];
      ta += (u < c1 ? 1u : 0u) | (u < c2 ? 0x10000u : 0u);
      tb += (u < c3 ? 1u : 0u);
    }
#pragma unroll
    for (int s=32;s>0;s>>=1){ ta += __shfl_down(ta, s, 64); tb += __shfl_down(tb, s, 64); }
    if (lane==0){ cbufA[par][wid] = ta; cbufB[par][wid] = tb; }
    __syncthreads();
    unsigned sa = 0, sb = 0;
#pragma unroll
    for (int i2=0;i2<16;i2++){ sa += cbufA[par][i2]; sb += cbufB[par][i2]; }
    int n1 = (int)(sa & 0xFFFFu), n2 = (int)(sa >> 16), n3 = (int)sb;
    if (n3 < KSEL){ T = c3; cntBelow = n3; }
    else if (n2 < KSEL){ T = c2; cntBelow = n2; }
    else if (n1 < KSEL){ T = c1; cntBelow = n1; }
    par ^= 1;
  }
  int kneed = KSEL - cntBelow;

  if (tid==0) tieCnt = 0;
  __syncthreads();
  float sx=0.f, sy=0.f, sz=0.f;
#pragma unroll
  for (int q=0;q<16;q++){
    unsigned u = ur[q];
    if (u < T){
      const float* p = cv + (size_t)(tid + q*1024)*3;
      sx += p[0]; sy += p[1]; sz += p[2];
    } else if (u == T){
      int pos = atomicAdd(&tieCnt, 1);
      if (pos < 256) tieIdx[pos] = tid + q*1024;
    }
  }
  __syncthreads();
  sx = block_sum(sx, red);
  sy = block_sum(sy, red);
  sz = block_sum(sz, red);
  if (tid==0){
    int mm = tieCnt < 256 ? tieCnt : 256;
    for (int t=0;t<kneed;t++){
      int best=-1, bi=0x7fffffff;
      for (int q=0;q<mm;q++){ int v = tieIdx[q]; if (v < bi){ bi=v; best=q; } }
      if (best >= 0){
        tieIdx[best] = 0x7fffffff;
        const float* p = cv + (size_t)bi*3;
        sx += p[0]; sy += p[1]; sz += p[2];
      }
    }
    centerpf[16 + b*3 + 0] = sx/KSEL - cx;
    centerpf[16 + b*3 + 1] = sy/KSEL - cy;
    centerpf[16 + b*3 + 2] = sz/KSEL - cz;
  }
}

/* ---------- refine: LSTM finish + decoder + canvas append + enc12 of the
   new 64-pt tile (f2buf output; enc3 follows as separate dispatch). 18x4
   blocks, each owns exactly 64 new points (192 outputs). ---------- */
__global__ __launch_bounds__(256) void refine12_kernel(
    float* __restrict__ canvas, const float* __restrict__ gpart,
    const float* __restrict__ centerpf,
    const float* __restrict__ c_in, float* __restrict__ c_out,
    float* __restrict__ h_out,
    const float* __restrict__ wih,
    const float* __restrict__ bih, const float* __restrict__ bhh,
    const float* __restrict__ rw1, const float* __restrict__ rb1,
    const float* __restrict__ rw2, const float* __restrict__ rb2,
    const float* __restrict__ w1, const float* __restrict__ b1,
    const float* __restrict__ w2, const float* __restrict__ b2,
    float* __restrict__ f2buf, int N)
{
  __shared__ float sG[512];
  __shared__ float sH[HD];
  __shared__ float sRf[HD];
  __shared__ float sP[192];
  int g = blockIdx.x, b = blockIdx.y;
  int tid = threadIdx.x;
  float cx = centerpf[b*3+0], cy = centerpf[b*3+1], cz = centerpf[b*3+2];
  float fx = centerpf[16+b*3+0], fy = centerpf[16+b*3+1], fz = centerpf[16+b*3+2];
#pragma unroll
  for (int half=0; half<2; half++){
    int o = tid + half*256;
    float gg = bih[o] + bhh[o];
    for (int cc=0; cc<32; cc++) gg += gpart[(size_t)cc*(BB*512) + b*512 + o];
    gg += cx*wih[(size_t)256*512+o] + cy*wih[(size_t)257*512+o] + cz*wih[(size_t)258*512+o];
    gg += fx*wih[(size_t)259*512+o] + fy*wih[(size_t)260*512+o] + fz*wih[(size_t)261*512+o];
    sG[o] = gg;
  }
  __syncthreads();
  if (tid < HD){
    float gi=sG[tid], gf=sG[128+tid], gg2=sG[256+tid], go=sG[384+tid];
    float cn = sigm(gf)*c_in[b*HD+tid] + sigm(gi)*tanhf(gg2);
    float hn = sigm(go)*tanhf(cn);
    sH[tid] = hn;
    if (g==0){ c_out[b*HD+tid]=cn; h_out[b*HD+tid]=hn; }
  }
  __syncthreads();
  if (tid < HD){
    float a = rb1[tid];
    for (int k=0;k<HD;k++) a += sH[k]*rw1[k*HD + tid];
    sRf[tid] = fmaxf(a, 0.f);
  }
  __syncthreads();
  /* decoder: this block's 192 outputs = 64 points */
  if (tid < 192){
    int o = g*192 + tid;
    float a = rb2[o];
    for (int k=0;k<HD;k++) a += sRf[k]*rw2[(size_t)k*(NEWP*3) + o];
    float val = a*0.02f + centerpf[b*3 + (tid%3)];
    sP[tid] = val;
    canvas[((size_t)b*NMAX + N)*3 + o] = val;
  }
  __syncthreads();
  /* enc12 of the 64 fresh points: thread = (p = tid&63, c = tid>>6).
     Wave-uniform c -> scalar w2 rows; proven f1[64]+a[16] k-outer shape. */
  {
    int p = tid & 63;
    int c = tid >> 6;               /* 0..3, = wave id */
    float p0 = sP[p*3], p1 = sP[p*3+1], p2 = sP[p*3+2];
    float f1[64];
#pragma unroll
    for (int j=0;j<64;j++)
      f1[j] = fmaxf(0.f, b1[j] + p0*w1[j] + p1*w1[64+j] + p2*w1[128+j]);
    int base = b*N0 + g*64 + p;     /* local new-point index < 1152 */
#pragma unroll
    for (int sub=0; sub<2; sub++){
      int j0 = c*32 + sub*16;
      float a[16];
      const float* b2p = b2 + j0;
#pragma unroll
      for (int j=0;j<16;j++) a[j] = b2p[j];
#pragma unroll
      for (int k=0;k<64;k++){
        const float* wr = w2 + k*128 + j0;   /* wave-uniform -> scalar */
#pragma unroll
        for (int j=0;j<16;j++) a[j] = fmaf(f1[k], wr[j], a[j]);
      }
#pragma unroll
      for (int j=0;j<16;j++)
        f2buf[(size_t)(j0 + j)*F2S + base] = fmaxf(a[j], 0.f);
    }
  }
}

/* ---------- chamfer (proven roofline config) ---------- */
__global__ __launch_bounds__(512) void chamfer_kernel(
    const float* __restrict__ canvas, const float* __restrict__ gt,
    unsigned* __restrict__ minAB, unsigned* __restrict__ minCD)
{
  __shared__ float sy0[1024], sy1[1024], sy2[1024], sny[1024];
  int id = blockIdx.x;
  int dir, rem;
  if (id < 32){ dir=0; rem=id; }
  else if (id < 64){ dir=1; rem=id-32; }
  else if (id < 160){ dir=2; rem=id-64; }
  else { dir=3; rem=id-160; }
  int b, xb, yb;
  if (dir < 2){ b = rem>>3; int l = rem&7; xb = l>>2; yb = l&3; }
  else if (dir == 2){ b = rem/24; int l = rem%24; xb = l>>2; yb = l&3; }
  else { b = rem/24; int l = rem%24; xb = l/12; yb = l%12; }

  int Nx, Ny; const float* X; const float* Y; unsigned* mp;
  if (dir==0){      Nx=N0;   Ny=N0;   X=canvas+(size_t)b*NMAX*3;       Y=gt+(size_t)b*N0*3;            mp=minAB + b*N0; }
  else if (dir==1){ Nx=N0;   Ny=N0;   X=gt+(size_t)b*N0*3;             Y=canvas+(size_t)b*NMAX*3;      mp=minAB + BB*N0 + b*N0; }
  else if (dir==2){ Nx=NNEW; Ny=N0;   X=canvas+((size_t)b*NMAX+N0)*3;  Y=gt+(size_t)b*N0*3;            mp=minCD + b*NNEW; }
  else {            Nx=N0;   Ny=NNEW; X=gt+(size_t)b*N0*3;             Y=canvas+((size_t)b*NMAX+N0)*3; mp=minCD + BB*NNEW + b*N0; }

  int xbase = xb*2048;
  int ybase = yb*1024;
  int tn = min(1024, Ny - ybase);
  int tid = threadIdx.x;
  for (int t=tid; t<tn; t+=512){
    const float* yp = Y + (size_t)(ybase+t)*3;
    float y0=yp[0], y1=yp[1], y2=yp[2];
    sy0[t]=y0; sy1[t]=y1; sy2[t]=y2; sny[t]=y0*y0+y1*y1+y2*y2;
  }
  __syncthreads();

  float X0[4],X1[4],X2[4],NXr[4],MN[4]; int XI[4]; bool VA[4];
#pragma unroll
  for (int q=0;q<4;q++){
    int x = xbase + q*512 + tid;
    VA[q] = x < Nx;
    int xc = VA[q] ? x : 0;
    const float* xp = X + (size_t)xc*3;
    X0[q]=xp[0]; X1[q]=xp[1]; X2[q]=xp[2];
    NXr[q] = X0[q]*X0[q] + X1[q]*X1[q] + X2[q]*X2[q];
    MN[q] = 3.4e38f; XI[q] = xc;
  }
  const float4* v0 = (const float4*)sy0;
  const float4* v1 = (const float4*)sy1;
  const float4* v2 = (const float4*)sy2;
  const float4* vn = (const float4*)sny;
  int j4n = tn >> 2;
  for (int j=0;j<j4n;j++){
    float4 a0 = v0[j], a1 = v1[j], a2 = v2[j], an = vn[j];
#pragma unroll
    for (int e=0;e<4;e++){
      float y0 = ((const float*)&a0)[e];
      float y1 = ((const float*)&a1)[e];
      float y2 = ((const float*)&a2)[e];
      float ny = ((const float*)&an)[e];
#pragma unroll
      for (int q=0;q<4;q++){
        float dot = fmaf(X0[q], y0, fmaf(X1[q], y1, X2[q]*y2));
        MN[q] = fminf(MN[q], fmaf(-2.f, dot, ny));
      }
    }
  }
  for (int j=j4n*4; j<tn; j++){
    float y0=sy0[j], y1=sy1[j], y2=sy2[j], ny=sny[j];
#pragma unroll
    for (int q=0;q<4;q++){
      float dot = fmaf(X0[q], y0, fmaf(X1[q], y1, X2[q]*y2));
      MN[q] = fminf(MN[q], fmaf(-2.f, dot, ny));
    }
  }
#pragma unroll
  for (int q=0;q<4;q++)
    if (VA[q]) atomicMin(&mp[XI[q]], enc_f(MN[q] + NXr[q]));
}

__global__ __launch_bounds__(256) void chamfer_reduce_kernel(
    const unsigned* __restrict__ minAB, const unsigned* __restrict__ minCD,
    float* __restrict__ acc)
{
  __shared__ float red[16];
  int s = blockIdx.x, dir = s>>2, b = s&3;
  const unsigned* mp; int len;
  if (dir==0){      mp=minAB + b*N0;            len=N0; }
  else if (dir==1){ mp=minAB + BB*N0 + b*N0;    len=N0; }
  else if (dir==2){ mp=minCD + b*NNEW;          len=NNEW; }
  else {            mp=minCD + BB*NNEW + b*N0;  len=N0; }
  float v = 0.f;
  for (int i=threadIdx.x;i<len;i+=256) v += dec_f(mp[i]);
  v = block_sum(v, red);
  if (threadIdx.x==0) acc[s] = v;
}

__global__ void finish_kernel(const float* __restrict__ acc, float* __restrict__ out)
{
  if (threadIdx.x == 0 && blockIdx.x == 0){
    float cd1 = 0.f, cd2 = 0.f;
    for (int b=0;b<BB;b++) cd1 += acc[b]/(float)N0 + acc[4+b]/(float)N0;
    for (int b=0;b<BB;b++) cd2 += acc[8+b]/(float)NNEW + acc[12+b]/(float)N0;
    out[0] = 0.1f*(cd1/BB) + 1.0f*(cd2/BB);
  }
}

extern "C" void kernel_launch(void* const* d_in, const int* in_sizes, int n_in,
                              void* d_out, int out_size, void* d_ws, size_t ws_size,
                              hipStream_t stream) {
  (void)in_sizes; (void)n_in; (void)out_size; (void)ws_size;
  const float* points   = (const float*)d_in[0];
  const float* gt       = (const float*)d_in[1];
  const float* enc_w1   = (const float*)d_in[2];
  const float* enc_b1   = (const float*)d_in[3];
  const float* enc_w2   = (const float*)d_in[4];
  const float* enc_b2   = (const float*)d_in[5];
  const float* enc_w3   = (const float*)d_in[6];
  const float* enc_b3   = (const float*)d_in[7];
  const float* att_w1   = (const float*)d_in[8];
  const float* att_b1   = (const float*)d_in[9];
  const float* att_w2   = (const float*)d_in[10];
  const float* att_b2   = (const float*)d_in[11];
  const float* lstm_wih = (const float*)d_in[12];
  const float* lstm_whh = (const float*)d_in[13];
  const float* lstm_bih = (const float*)d_in[14];
  const float* lstm_bhh = (const float*)d_in[15];
  const float* ref_w1   = (const float*)d_in[16];
  const float* ref_b1   = (const float*)d_in[17];
  const float* ref_w2   = (const float*)d_in[18];
  const float* ref_b2   = (const float*)d_in[19];
  float* out = (float*)d_out;

  float* ws       = (float*)d_ws;
  float* canvas   = ws + OFF_CANVAS;
  unsigned* minAB = (unsigned*)(ws + OFF_MINAB);
  unsigned* minCD = (unsigned*)(ws + OFF_MINCD);
  unsigned* gmaxp = (unsigned*)(ws + OFF_GMAX);
  float* hb       = ws + OFF_H;
  float* cb       = ws + OFF_C;
  float* acc      = ws + OFF_ACC;
  float* centerb  = ws + OFF_CENTER;
  float* partb    = ws + OFF_PART;
  float* gpartb   = ws + OFF_GPART;
  float* f2buf    = ws + OFF_F2;

  init_kernel<<<dim3(128), 512, 0, stream>>>(points, canvas, minAB, minCD, gmaxp, hb, cb);
  enc12_kernel<<<dim3(16, BB, 8), 256, 0, stream>>>(canvas, enc_w1, enc_b1, enc_w2, enc_b2, f2buf, 0, N0);
  enc3_kernel<<<dim3(16, BB, 16), 256, 0, stream>>>(f2buf, enc_w3, enc_b3, gmaxp, N0);

  for (int t=0; t<NSTEPS; t++){
    int N   = N0 + t*NEWP;
    int nch = (N + 511) >> 9;
    float* h_in  = hb + (t&1)*BB*HD;
    float* h_out = hb + ((t+1)&1)*BB*HD;
    float* c_in  = cb + (t&1)*BB*HD;
    float* c_out = cb + ((t+1)&1)*BB*HD;
    sl_kernel<<<dim3(4*nch + 32), 512, 0, stream>>>(canvas, att_w1, att_b1, att_w2, att_b2,
                                                    gmaxp, h_in, lstm_wih, lstm_whh,
                                                    partb, gpartb, N, nch);
    stepA_kernel<<<dim3(BB), 1024, 0, stream>>>(canvas, partb, centerb, N, nch);
    refine12_kernel<<<dim3(18, BB), 256, 0, stream>>>(canvas, gpartb, centerb,
                                                      c_in, c_out, h_out,
                                                      lstm_wih, lstm_bih, lstm_bhh,
                                                      ref_w1, ref_b1, ref_w2, ref_b2,
                                                      enc_w1, enc_b1, enc_w2, enc_b2,
                                                      f2buf, N);
    enc3_kernel<<<dim3(5, BB, 16), 256, 0, stream>>>(f2buf, enc_w3, enc_b3, gmaxp, NEWP);
  }

  chamfer_kernel<<<dim3(256), 512, 0, stream>>>(canvas, gt, minAB, minCD);
  chamfer_reduce_kernel<<<dim3(16), 256, 0, stream>>>(minAB, minCD, acc);
  finish_kernel<<<1, 64, 0, stream>>>(acc, out);
}

// Round 12
// 1061.105 us; speedup vs baseline: 1.1532x; 1.1532x over previous
//
#include <hip/hip_runtime.h>
#include <math.h>

#define BB 4
#define N0 4096
#define NEWP 1152
#define GD 256
#define HD 128
#define KSEL 64
#define NSTEPS 10
#define NMAX (N0 + NSTEPS*NEWP)   /* 15616 */
#define NNEW (NSTEPS*NEWP)        /* 11520 */
#define F2S (BB*N0)               /* 16384: stride of f2buf[k][b*N0+i] */

/* ---- workspace layout (float offsets) ---- */
#define OFF_CANVAS 0
#define OFF_MINAB  (OFF_CANVAS + BB*NMAX*3)
#define OFF_MINCD  (OFF_MINAB + 2*BB*N0)
#define OFF_GMAX   (OFF_MINCD + BB*NNEW + BB*N0)
#define OFF_H      (OFF_GMAX + BB*GD)          /* 2 buffers */
#define OFF_C      (OFF_H + 2*BB*HD)           /* 2 buffers */
#define OFF_ACC    (OFF_C + 2*BB*HD)
#define OFF_CENTER (OFF_ACC + 16)
#define OFF_PART   (OFF_CENTER + 32)           /* BB*32*8 */
#define OFF_GPART  (OFF_PART + BB*32*8)        /* 32*BB*512 */
#define OFF_F2     (OFF_GPART + 32*BB*512)     /* 128*F2S */
#define WS_FLOATS  (OFF_F2 + 128*F2S)

__device__ __forceinline__ unsigned enc_f(float f){
  unsigned u = __float_as_uint(f);
  return (u & 0x80000000u) ? ~u : (u | 0x80000000u);
}
__device__ __forceinline__ float dec_f(unsigned e){
  unsigned u = (e & 0x80000000u) ? (e & 0x7fffffffu) : ~e;
  return __uint_as_float(u);
}
__device__ __forceinline__ float sigm(float x){ return 1.f/(1.f+expf(-x)); }

__device__ __forceinline__ float block_sum(float v, volatile float* red){
#pragma unroll
  for (int s=32;s>0;s>>=1) v += __shfl_down(v, s, 64);
  int lane = threadIdx.x & 63, w = threadIdx.x >> 6, nw = blockDim.x >> 6;
  __syncthreads();
  if (lane==0) red[w] = v;
  __syncthreads();
  if (w==0){
    float x = (lane < nw) ? red[lane] : 0.f;
#pragma unroll
    for (int s=8;s>0;s>>=1) x += __shfl_down(x, s, 64);
    if (lane==0) red[0] = x;
  }
  __syncthreads();
  float r = red[0];
  __syncthreads();
  return r;
}
__device__ __forceinline__ float block_max(float v, volatile float* red){
#pragma unroll
  for (int s=32;s>0;s>>=1) v = fmaxf(v, __shfl_down(v, s, 64));
  int lane = threadIdx.x & 63, w = threadIdx.x >> 6, nw = blockDim.x >> 6;
  __syncthreads();
  if (lane==0) red[w] = v;
  __syncthreads();
  if (w==0){
    float x = (lane < nw) ? red[lane] : -3.4e38f;
#pragma unroll
    for (int s=8;s>0;s>>=1) x = fmaxf(x, __shfl_down(x, s, 64));
    if (lane==0) red[0] = x;
  }
  __syncthreads();
  float r = red[0];
  __syncthreads();
  return r;
}

/* ---------- init ---------- */
__global__ __launch_bounds__(512) void init_kernel(
    const float* __restrict__ points,
    float* __restrict__ canvas, unsigned* __restrict__ minAB,
    unsigned* __restrict__ minCD, unsigned* __restrict__ gmax,
    float* __restrict__ h, float* __restrict__ c)
{
  int gid = blockIdx.x*512 + threadIdx.x;
  if (gid < BB*N0*3){
    int b = gid/(N0*3), r = gid - b*(N0*3);
    canvas[(size_t)b*NMAX*3 + r] = points[gid];
  }
  if (gid < 2*BB*N0) minAB[gid] = 0xFFFFFFFFu;
  if (gid < BB*NNEW + BB*N0) minCD[gid] = 0xFFFFFFFFu;
  if (gid < BB*GD) gmax[gid] = 0u;
  if (gid < 2*BB*HD){ h[gid]=0.f; c[gid]=0.f; }
}

/* ---------- enc layers 1+2: thread=point, jc z-chunk owns 16 of 128 outs ---------- */
__global__ __launch_bounds__(256) void enc12_kernel(
    const float* __restrict__ canvas, const float* __restrict__ w1,
    const float* __restrict__ b1, const float* __restrict__ w2,
    const float* __restrict__ b2, float* __restrict__ f2buf,
    int off, int M)
{
  int b = blockIdx.y;
  int jc = blockIdx.z;            /* 0..7 */
  int i = blockIdx.x*256 + threadIdx.x;
  int ii = (i < M) ? i : 0;
  const float* p = canvas + (size_t)(b*NMAX + off + ii)*3;
  float p0 = p[0], p1 = p[1], p2 = p[2];
  float f1[64];
#pragma unroll
  for (int j=0;j<64;j++)
    f1[j] = fmaxf(0.f, b1[j] + p0*w1[j] + p1*w1[64+j] + p2*w1[128+j]);
  float a[16];
  const float* b2p = b2 + jc*16;
#pragma unroll
  for (int j=0;j<16;j++) a[j] = b2p[j];
#pragma unroll
  for (int k=0;k<64;k++){
    const float* wr = w2 + k*128 + jc*16;   /* wave-uniform -> scalar */
#pragma unroll
    for (int j=0;j<16;j++) a[j] = fmaf(f1[k], wr[j], a[j]);
  }
  if (i < M){
    int base = b*N0 + i;
#pragma unroll
    for (int j=0;j<16;j++)
      f2buf[(size_t)(jc*16 + j)*F2S + base] = fmaxf(a[j], 0.f);
  }
}

/* ---------- enc layer 3 + running max-pool ---------- */
__global__ __launch_bounds__(256) void enc3_kernel(
    const float* __restrict__ f2buf, const float* __restrict__ w3,
    const float* __restrict__ b3, unsigned* __restrict__ gmax, int M)
{
  int b = blockIdx.y;
  int dc = blockIdx.z;            /* 0..15 */
  int i = blockIdx.x*256 + threadIdx.x;
  bool act = i < M;
  int ii = act ? i : 0;
  const float* fp = f2buf + b*N0 + ii;
  float a[16];
  const float* b3p = b3 + dc*16;
#pragma unroll
  for (int d=0;d<16;d++) a[d] = b3p[d];
  for (int k=0;k<128;k++){
    float fk = fp[(size_t)k*F2S];           /* coalesced */
    const float* wr = w3 + k*256 + dc*16;   /* wave-uniform -> scalar */
#pragma unroll
    for (int d=0;d<16;d++) a[d] = fmaf(fk, wr[d], a[d]);
  }
#pragma unroll
  for (int d=0;d<16;d++){
    float v = act ? a[d] : -3.4e38f;
#pragma unroll
    for (int s=32;s>0;s>>=1) v = fmaxf(v, __shfl_down(v, s, 64));
    if ((threadIdx.x & 63) == 0) atomicMax(&gmax[b*GD + dc*16 + d], enc_f(v));
  }
}

/* ---------- scores partials + lstm partials, one dispatch ---------- */
__global__ __launch_bounds__(512) void sl_kernel(
    const float* __restrict__ canvas, const float* __restrict__ aw1,
    const float* __restrict__ ab1, const float* __restrict__ aw2,
    const float* __restrict__ ab2, const unsigned* __restrict__ gmax,
    const float* __restrict__ h_in,
    const float* __restrict__ wih, const float* __restrict__ whh,
    float* __restrict__ part, float* __restrict__ gpart, int N, int nch)
{
  __shared__ float sBatt[128];
  __shared__ float red[16];
  __shared__ float sV[BB][12];
  int blk = blockIdx.x;
  int tid = threadIdx.x;
  if (blk < 4*nch){
    int b = blk / nch, ch = blk - b*nch;
    if (tid < 128){
      float a = ab1[tid];
      for (int k=0;k<GD;k++) a += dec_f(gmax[b*GD+k]) * aw1[(3+k)*128 + tid];
      for (int k=0;k<HD;k++) a += h_in[b*HD+k] * aw1[(3+GD+k)*128 + tid];
      sBatt[tid] = a;
    }
    __syncthreads();
    int i = ch*512 + tid;
    bool act = i < N;
    float p0=0.f,p1=0.f,p2=0.f,s=-3.4e38f;
    if (act){
      const float* pp = canvas + (size_t)(b*NMAX + i)*3;
      p0=pp[0]; p1=pp[1]; p2=pp[2];
      s = ab2[0];
      for (int j=0;j<128;j++){
        float v = sBatt[j] + p0*aw1[j] + p1*aw1[128+j] + p2*aw1[256+j];
        s += fmaxf(v, 0.f)*aw2[j];
      }
    }
    float mb = block_max(s, red);
    float e = act ? expf(s - mb) : 0.f;
    float se = block_sum(e, red);
    float wx = block_sum(e*p0, red);
    float wy = block_sum(e*p1, red);
    float wz = block_sum(e*p2, red);
    if (tid==0){
      float* pr = part + (size_t)(b*32 + ch)*8;
      pr[0]=mb; pr[1]=se; pr[2]=wx; pr[3]=wy; pr[4]=wz;
    }
  } else {
    int cc = blk - 4*nch;   /* 0..31 */
    if (tid < BB*12){
      int b = tid/12, j = tid - b*12;
      int r = cc*12 + j;
      sV[b][j] = (r < 256) ? dec_f(gmax[b*GD + r]) : h_in[b*HD + (r-256)];
    }
    __syncthreads();
    float a0=0.f,a1=0.f,a2=0.f,a3=0.f;
#pragma unroll
    for (int j=0;j<12;j++){
      int r = cc*12 + j;
      const float* wr = (r < 256) ? (wih + (size_t)r*512) : (whh + (size_t)(r-256)*512);
      float wvv = wr[tid];
      a0 += sV[0][j]*wvv; a1 += sV[1][j]*wvv;
      a2 += sV[2][j]*wvv; a3 += sV[3][j]*wvv;
    }
    float* gp = gpart + (size_t)cc*(BB*512);
    gp[0*512+tid]=a0; gp[1*512+tid]=a1; gp[2*512+tid]=a2; gp[3*512+tid]=a3;
  }
}

/* ---------- stepA: center + top-64 threshold + patch mean ---------- */
__global__ __launch_bounds__(1024) void stepA_kernel(
    const float* __restrict__ canvas, const float* __restrict__ part,
    float* __restrict__ centerpf, int N, int nch)
{
  __shared__ float red[16];
  __shared__ float sC[3];
  __shared__ unsigned cbufA[2][16];
  __shared__ unsigned cbufB[2][16];
  __shared__ int tieCnt;
  __shared__ int tieIdx[256];

  int b = blockIdx.x;
  int tid = threadIdx.x;
  int lane = tid & 63, wid = tid >> 6;
  const float* cv = canvas + (size_t)b*NMAX*3;

  float pm=-3.4e38f, pse=0.f, pwx=0.f, pwy=0.f, pwz=0.f;
  if (tid < nch){
    const float* pp = part + (size_t)(b*32 + tid)*8;
    pm=pp[0]; pse=pp[1]; pwx=pp[2]; pwy=pp[3]; pwz=pp[4];
  }
  float M = block_max(pm, red);
  float w = (tid < nch) ? expf(pm - M) : 0.f;
  float se = block_sum(pse*w, red);
  float wx = block_sum(pwx*w, red);
  float wy = block_sum(pwy*w, red);
  float wz = block_sum(pwz*w, red);
  if (tid==0){ sC[0]=wx/se; sC[1]=wy/se; sC[2]=wz/se; }
  __syncthreads();
  float cx=sC[0], cy=sC[1], cz=sC[2];
  if (tid<3) centerpf[b*3+tid] = sC[tid];

  unsigned ur[16];
#pragma unroll
  for (int q=0;q<16;q++){
    ur[q] = 0xFFFFFFFFu;
    int i = tid + q*1024;
    if (i < N){
      const float* p = cv + (size_t)i*3;
      float dx=p[0]-cx, dy=p[1]-cy, dz=p[2]-cz;
      ur[q] = __float_as_uint(dx*dx + dy*dy + dz*dz);
    }
  }

  unsigned T = 0u;
  int cntBelow = 0;
  int par = 0;
  {
    unsigned cand = 1u<<30;
    unsigned tc = 0;
#pragma unroll
    for (int q=0;q<16;q++) tc += (ur[q] < cand) ? 1u : 0u;
#pragma unroll
    for (int s=32;s>0;s>>=1) tc += __shfl_down(tc, s, 64);
    if (lane==0) cbufA[par][wid] = tc;
    __syncthreads();
    unsigned tot = 0;
#pragma unroll
    for (int i2=0;i2<16;i2++) tot += cbufA[par][i2];
    if ((int)tot < KSEL){ T = cand; cntBelow = (int)tot; }
    par ^= 1;
  }
  for (int bit=29; bit>=1; bit-=2){
    unsigned q1 = 1u<<(bit-1);
    unsigned c1 = T + q1, c2 = T + 2u*q1, c3 = T + 3u*q1;
    unsigned ta = 0, tb = 0;
#pragma unroll
    for (int q=0;q<16;q++){
      unsigned u = ur[q];
      ta += (u < c1 ? 1u : 0u) | (u < c2 ? 0x10000u : 0u);
      tb += (u < c3 ? 1u : 0u);
    }
#pragma unroll
    for (int s=32;s>0;s>>=1){ ta += __shfl_down(ta, s, 64); tb += __shfl_down(tb, s, 64); }
    if (lane==0){ cbufA[par][wid] = ta; cbufB[par][wid] = tb; }
    __syncthreads();
    unsigned sa = 0, sb = 0;
#pragma unroll
    for (int i2=0;i2<16;i2++){ sa += cbufA[par][i2]; sb += cbufB[par][i2]; }
    int n1 = (int)(sa & 0xFFFFu), n2 = (int)(sa >> 16), n3 = (int)sb;
    if (n3 < KSEL){ T = c3; cntBelow = n3; }
    else if (n2 < KSEL){ T = c2; cntBelow = n2; }
    else if (n1 < KSEL){ T = c1; cntBelow = n1; }
    par ^= 1;
  }
  int kneed = KSEL - cntBelow;

  if (tid==0) tieCnt = 0;
  __syncthreads();
  float sx=0.f, sy=0.f, sz=0.f;
#pragma unroll
  for (int q=0;q<16;q++){
    unsigned u = ur[q];
    if (u < T){
      const float* p = cv + (size_t)(tid + q*1024)*3;
      sx += p[0]; sy += p[1]; sz += p[2];
    } else if (u == T){
      int pos = atomicAdd(&tieCnt, 1);
      if (pos < 256) tieIdx[pos] = tid + q*1024;
    }
  }
  __syncthreads();
  sx = block_sum(sx, red);
  sy = block_sum(sy, red);
  sz = block_sum(sz, red);
  if (tid==0){
    int mm = tieCnt < 256 ? tieCnt : 256;
    for (int t=0;t<kneed;t++){
      int best=-1, bi=0x7fffffff;
      for (int q=0;q<mm;q++){ int v = tieIdx[q]; if (v < bi){ bi=v; best=q; } }
      if (best >= 0){
        tieIdx[best] = 0x7fffffff;
        const float* p = cv + (size_t)bi*3;
        sx += p[0]; sy += p[1]; sz += p[2];
      }
    }
    centerpf[16 + b*3 + 0] = sx/KSEL - cx;
    centerpf[16 + b*3 + 1] = sy/KSEL - cy;
    centerpf[16 + b*3 + 2] = sz/KSEL - cz;
  }
}

/* ---------- refine: LSTM finish + decoder + canvas append ---------- */
__global__ __launch_bounds__(256) void refine_kernel(
    float* __restrict__ canvas, const float* __restrict__ gpart,
    const float* __restrict__ centerpf,
    const float* __restrict__ c_in, float* __restrict__ c_out,
    float* __restrict__ h_out,
    const float* __restrict__ wih,
    const float* __restrict__ bih, const float* __restrict__ bhh,
    const float* __restrict__ rw1, const float* __restrict__ rb1,
    const float* __restrict__ rw2, const float* __restrict__ rb2, int N)
{
  __shared__ float sG[512];
  __shared__ float sH[HD];
  __shared__ float sRf[HD];
  int g = blockIdx.x, b = blockIdx.y;
  int tid = threadIdx.x;
  float cx = centerpf[b*3+0], cy = centerpf[b*3+1], cz = centerpf[b*3+2];
  float fx = centerpf[16+b*3+0], fy = centerpf[16+b*3+1], fz = centerpf[16+b*3+2];
#pragma unroll
  for (int half=0; half<2; half++){
    int o = tid + half*256;
    float gg = bih[o] + bhh[o];
    for (int cc=0; cc<32; cc++) gg += gpart[(size_t)cc*(BB*512) + b*512 + o];
    gg += cx*wih[(size_t)256*512+o] + cy*wih[(size_t)257*512+o] + cz*wih[(size_t)258*512+o];
    gg += fx*wih[(size_t)259*512+o] + fy*wih[(size_t)260*512+o] + fz*wih[(size_t)261*512+o];
    sG[o] = gg;
  }
  __syncthreads();
  if (tid < HD){
    float gi=sG[tid], gf=sG[128+tid], gg2=sG[256+tid], go=sG[384+tid];
    float cn = sigm(gf)*c_in[b*HD+tid] + sigm(gi)*tanhf(gg2);
    float hn = sigm(go)*tanhf(cn);
    sH[tid] = hn;
    if (g==0){ c_out[b*HD+tid]=cn; h_out[b*HD+tid]=hn; }
  }
  __syncthreads();
  if (tid < HD){
    float a = rb1[tid];
    for (int k=0;k<HD;k++) a += sH[k]*rw1[k*HD + tid];
    sRf[tid] = fmaxf(a, 0.f);
  }
  __syncthreads();
  int o = g*256 + tid;
  if (o < NEWP*3){
    float a = rb2[o];
    for (int k=0;k<HD;k++) a += sRf[k]*rw2[(size_t)k*(NEWP*3) + o];
    canvas[((size_t)b*NMAX + N)*3 + o] = a*0.02f + centerpf[b*3 + (o%3)];
  }
}

/* ---------- chamfer: stage -2y in LDS, fold |y|^2 into innermost fma.
   4 VALU per pair (3 fma + 1 fmin). ---------- */
__global__ __launch_bounds__(512) void chamfer_kernel(
    const float* __restrict__ canvas, const float* __restrict__ gt,
    unsigned* __restrict__ minAB, unsigned* __restrict__ minCD)
{
  __shared__ float sy0[1024], sy1[1024], sy2[1024], sny[1024];
  int id = blockIdx.x;
  int dir, rem;
  if (id < 32){ dir=0; rem=id; }
  else if (id < 64){ dir=1; rem=id-32; }
  else if (id < 160){ dir=2; rem=id-64; }
  else { dir=3; rem=id-160; }
  int b, xb, yb;
  if (dir < 2){ b = rem>>3; int l = rem&7; xb = l>>2; yb = l&3; }
  else if (dir == 2){ b = rem/24; int l = rem%24; xb = l>>2; yb = l&3; }
  else { b = rem/24; int l = rem%24; xb = l/12; yb = l%12; }

  int Nx, Ny; const float* X; const float* Y; unsigned* mp;
  if (dir==0){      Nx=N0;   Ny=N0;   X=canvas+(size_t)b*NMAX*3;       Y=gt+(size_t)b*N0*3;            mp=minAB + b*N0; }
  else if (dir==1){ Nx=N0;   Ny=N0;   X=gt+(size_t)b*N0*3;             Y=canvas+(size_t)b*NMAX*3;      mp=minAB + BB*N0 + b*N0; }
  else if (dir==2){ Nx=NNEW; Ny=N0;   X=canvas+((size_t)b*NMAX+N0)*3;  Y=gt+(size_t)b*N0*3;            mp=minCD + b*NNEW; }
  else {            Nx=N0;   Ny=NNEW; X=gt+(size_t)b*N0*3;             Y=canvas+((size_t)b*NMAX+N0)*3; mp=minCD + BB*NNEW + b*N0; }

  int xbase = xb*2048;
  int ybase = yb*1024;
  int tn = min(1024, Ny - ybase);
  int tid = threadIdx.x;
  for (int t=tid; t<tn; t+=512){
    const float* yp = Y + (size_t)(ybase+t)*3;
    float y0=yp[0], y1=yp[1], y2=yp[2];
    sy0[t]=-2.f*y0; sy1[t]=-2.f*y1; sy2[t]=-2.f*y2; sny[t]=y0*y0+y1*y1+y2*y2;
  }
  __syncthreads();

  float X0[4],X1[4],X2[4],NXr[4],MN[4]; int XI[4]; bool VA[4];
#pragma unroll
  for (int q=0;q<4;q++){
    int x = xbase + q*512 + tid;
    VA[q] = x < Nx;
    int xc = VA[q] ? x : 0;
    const float* xp = X + (size_t)xc*3;
    X0[q]=xp[0]; X1[q]=xp[1]; X2[q]=xp[2];
    NXr[q] = X0[q]*X0[q] + X1[q]*X1[q] + X2[q]*X2[q];
    MN[q] = 3.4e38f; XI[q] = xc;
  }
  const float4* v0 = (const float4*)sy0;
  const float4* v1 = (const float4*)sy1;
  const float4* v2 = (const float4*)sy2;
  const float4* vn = (const float4*)sny;
  int j4n = tn >> 2;
  for (int j=0;j<j4n;j++){
    float4 a0 = v0[j], a1 = v1[j], a2 = v2[j], an = vn[j];
#pragma unroll
    for (int e=0;e<4;e++){
      float y0 = ((const float*)&a0)[e];
      float y1 = ((const float*)&a1)[e];
      float y2 = ((const float*)&a2)[e];
      float ny = ((const float*)&an)[e];
#pragma unroll
      for (int q=0;q<4;q++){
        float d = fmaf(X0[q], y0, fmaf(X1[q], y1, fmaf(X2[q], y2, ny)));
        MN[q] = fminf(MN[q], d);
      }
    }
  }
  for (int j=j4n*4; j<tn; j++){
    float y0=sy0[j], y1=sy1[j], y2=sy2[j], ny=sny[j];
#pragma unroll
    for (int q=0;q<4;q++){
      float d = fmaf(X0[q], y0, fmaf(X1[q], y1, fmaf(X2[q], y2, ny)));
      MN[q] = fminf(MN[q], d);
    }
  }
#pragma unroll
  for (int q=0;q<4;q++)
    if (VA[q]) atomicMin(&mp[XI[q]], enc_f(MN[q] + NXr[q]));
}

__global__ __launch_bounds__(256) void chamfer_reduce_kernel(
    const unsigned* __restrict__ minAB, const unsigned* __restrict__ minCD,
    float* __restrict__ acc)
{
  __shared__ float red[16];
  int s = blockIdx.x, dir = s>>2, b = s&3;
  const unsigned* mp; int len;
  if (dir==0){      mp=minAB + b*N0;            len=N0; }
  else if (dir==1){ mp=minAB + BB*N0 + b*N0;    len=N0; }
  else if (dir==2){ mp=minCD + b*NNEW;          len=NNEW; }
  else {            mp=minCD + BB*NNEW + b*N0;  len=N0; }
  float v = 0.f;
  for (int i=threadIdx.x;i<len;i+=256) v += dec_f(mp[i]);
  v = block_sum(v, red);
  if (threadIdx.x==0) acc[s] = v;
}

__global__ void finish_kernel(const float* __restrict__ acc, float* __restrict__ out)
{
  if (threadIdx.x == 0 && blockIdx.x == 0){
    float cd1 = 0.f, cd2 = 0.f;
    for (int b=0;b<BB;b++) cd1 += acc[b]/(float)N0 + acc[4+b]/(float)N0;
    for (int b=0;b<BB;b++) cd2 += acc[8+b]/(float)NNEW + acc[12+b]/(float)N0;
    out[0] = 0.1f*(cd1/BB) + 1.0f*(cd2/BB);
  }
}

extern "C" void kernel_launch(void* const* d_in, const int* in_sizes, int n_in,
                              void* d_out, int out_size, void* d_ws, size_t ws_size,
                              hipStream_t stream) {
  (void)in_sizes; (void)n_in; (void)out_size; (void)ws_size;
  const float* points   = (const float*)d_in[0];
  const float* gt       = (const float*)d_in[1];
  const float* enc_w1   = (const float*)d_in[2];
  const float* enc_b1   = (const float*)d_in[3];
  const float* enc_w2   = (const float*)d_in[4];
  const float* enc_b2   = (const float*)d_in[5];
  const float* enc_w3   = (const float*)d_in[6];
  const float* enc_b3   = (const float*)d_in[7];
  const float* att_w1   = (const float*)d_in[8];
  const float* att_b1   = (const float*)d_in[9];
  const float* att_w2   = (const float*)d_in[10];
  const float* att_b2   = (const float*)d_in[11];
  const float* lstm_wih = (const float*)d_in[12];
  const float* lstm_whh = (const float*)d_in[13];
  const float* lstm_bih = (const float*)d_in[14];
  const float* lstm_bhh = (const float*)d_in[15];
  const float* ref_w1   = (const float*)d_in[16];
  const float* ref_b1   = (const float*)d_in[17];
  const float* ref_w2   = (const float*)d_in[18];
  const float* ref_b2   = (const float*)d_in[19];
  float* out = (float*)d_out;

  float* ws       = (float*)d_ws;
  float* canvas   = ws + OFF_CANVAS;
  unsigned* minAB = (unsigned*)(ws + OFF_MINAB);
  unsigned* minCD = (unsigned*)(ws + OFF_MINCD);
  unsigned* gmaxp = (unsigned*)(ws + OFF_GMAX);
  float* hb       = ws + OFF_H;
  float* cb       = ws + OFF_C;
  float* acc      = ws + OFF_ACC;
  float* centerb  = ws + OFF_CENTER;
  float* partb    = ws + OFF_PART;
  float* gpartb   = ws + OFF_GPART;
  float* f2buf    = ws + OFF_F2;

  init_kernel<<<dim3(128), 512, 0, stream>>>(points, canvas, minAB, minCD, gmaxp, hb, cb);
  enc12_kernel<<<dim3(16, BB, 8), 256, 0, stream>>>(canvas, enc_w1, enc_b1, enc_w2, enc_b2, f2buf, 0, N0);
  enc3_kernel<<<dim3(16, BB, 16), 256, 0, stream>>>(f2buf, enc_w3, enc_b3, gmaxp, N0);

  for (int t=0; t<NSTEPS; t++){
    int N   = N0 + t*NEWP;
    int nch = (N + 511) >> 9;
    float* h_in  = hb + (t&1)*BB*HD;
    float* h_out = hb + ((t+1)&1)*BB*HD;
    float* c_in  = cb + (t&1)*BB*HD;
    float* c_out = cb + ((t+1)&1)*BB*HD;
    sl_kernel<<<dim3(4*nch + 32), 512, 0, stream>>>(canvas, att_w1, att_b1, att_w2, att_b2,
                                                    gmaxp, h_in, lstm_wih, lstm_whh,
                                                    partb, gpartb, N, nch);
    stepA_kernel<<<dim3(BB), 1024, 0, stream>>>(canvas, partb, centerb, N, nch);
    refine_kernel<<<dim3(14, BB), 256, 0, stream>>>(canvas, gpartb, centerb,
                                                    c_in, c_out, h_out,
                                                    lstm_wih, lstm_bih, lstm_bhh,
                                                    ref_w1, ref_b1, ref_w2, ref_b2, N);
    if (t < NSTEPS-1){
      /* last step's encoder output is never consumed — skip it */
      enc12_kernel<<<dim3(5, BB, 8), 256, 0, stream>>>(canvas, enc_w1, enc_b1, enc_w2, enc_b2, f2buf, N, NEWP);
      enc3_kernel<<<dim3(5, BB, 16), 256, 0, stream>>>(f2buf, enc_w3, enc_b3, gmaxp, NEWP);
    }
  }

  chamfer_kernel<<<dim3(256), 512, 0, stream>>>(canvas, gt, minAB, minCD);
  chamfer_reduce_kernel<<<dim3(16), 256, 0, stream>>>(minAB, minCD, acc);
  finish_kernel<<<1, 64, 0, stream>>>(acc, out);
}

// Round 13
// 1034.765 us; speedup vs baseline: 1.1826x; 1.0255x over previous
//
#include <hip/hip_runtime.h>
#include <math.h>

#define BB 4
#define N0 4096
#define NEWP 1152
#define GD 256
#define HD 128
#define KSEL 64
#define NSTEPS 10
#define NMAX (N0 + NSTEPS*NEWP)   /* 15616 */
#define NNEW (NSTEPS*NEWP)        /* 11520 */
#define F2S (BB*N0)               /* 16384: stride of f2buf[k][b*N0+i] */

/* ---- workspace layout (float offsets) ---- */
#define OFF_CANVAS 0
#define OFF_MINAB  (OFF_CANVAS + BB*NMAX*3)
#define OFF_MINCD  (OFF_MINAB + 2*BB*N0)
#define OFF_GMAX   (OFF_MINCD + BB*NNEW + BB*N0)
#define OFF_H      (OFF_GMAX + BB*GD)          /* 2 buffers */
#define OFF_C      (OFF_H + 2*BB*HD)           /* 2 buffers */
#define OFF_ACC    (OFF_C + 2*BB*HD)
#define OFF_CENTER (OFF_ACC + 16)
#define OFF_PART   (OFF_CENTER + 32)           /* BB*32*8 */
#define OFF_GPART  (OFF_PART + BB*32*8)        /* 32*BB*512 */
#define OFF_F2     (OFF_GPART + 32*BB*512)     /* 128*F2S */
#define WS_FLOATS  (OFF_F2 + 128*F2S)

__device__ __forceinline__ unsigned enc_f(float f){
  unsigned u = __float_as_uint(f);
  return (u & 0x80000000u) ? ~u : (u | 0x80000000u);
}
__device__ __forceinline__ float dec_f(unsigned e){
  unsigned u = (e & 0x80000000u) ? (e & 0x7fffffffu) : ~e;
  return __uint_as_float(u);
}
__device__ __forceinline__ float sigm(float x){ return 1.f/(1.f+expf(-x)); }

__device__ __forceinline__ float block_sum(float v, volatile float* red){
#pragma unroll
  for (int s=32;s>0;s>>=1) v += __shfl_down(v, s, 64);
  int lane = threadIdx.x & 63, w = threadIdx.x >> 6, nw = blockDim.x >> 6;
  __syncthreads();
  if (lane==0) red[w] = v;
  __syncthreads();
  if (w==0){
    float x = (lane < nw) ? red[lane] : 0.f;
#pragma unroll
    for (int s=8;s>0;s>>=1) x += __shfl_down(x, s, 64);
    if (lane==0) red[0] = x;
  }
  __syncthreads();
  float r = red[0];
  __syncthreads();
  return r;
}
__device__ __forceinline__ float block_max(float v, volatile float* red){
#pragma unroll
  for (int s=32;s>0;s>>=1) v = fmaxf(v, __shfl_down(v, s, 64));
  int lane = threadIdx.x & 63, w = threadIdx.x >> 6, nw = blockDim.x >> 6;
  __syncthreads();
  if (lane==0) red[w] = v;
  __syncthreads();
  if (w==0){
    float x = (lane < nw) ? red[lane] : -3.4e38f;
#pragma unroll
    for (int s=8;s>0;s>>=1) x = fmaxf(x, __shfl_down(x, s, 64));
    if (lane==0) red[0] = x;
  }
  __syncthreads();
  float r = red[0];
  __syncthreads();
  return r;
}

/* ---------- init ---------- */
__global__ __launch_bounds__(512) void init_kernel(
    const float* __restrict__ points,
    float* __restrict__ canvas, unsigned* __restrict__ minAB,
    unsigned* __restrict__ minCD, unsigned* __restrict__ gmax,
    float* __restrict__ h, float* __restrict__ c)
{
  int gid = blockIdx.x*512 + threadIdx.x;
  if (gid < BB*N0*3){
    int b = gid/(N0*3), r = gid - b*(N0*3);
    canvas[(size_t)b*NMAX*3 + r] = points[gid];
  }
  if (gid < 2*BB*N0) minAB[gid] = 0xFFFFFFFFu;
  if (gid < BB*NNEW + BB*N0) minCD[gid] = 0xFFFFFFFFu;
  if (gid < BB*GD) gmax[gid] = 0u;
  if (gid < 2*BB*HD){ h[gid]=0.f; c[gid]=0.f; }
}

/* ---------- enc layers 1+2 (standalone, t=0 initial points) ---------- */
__global__ __launch_bounds__(256) void enc12_kernel(
    const float* __restrict__ canvas, const float* __restrict__ w1,
    const float* __restrict__ b1, const float* __restrict__ w2,
    const float* __restrict__ b2, float* __restrict__ f2buf,
    int off, int M)
{
  int b = blockIdx.y;
  int jc = blockIdx.z;            /* 0..7 */
  int i = blockIdx.x*256 + threadIdx.x;
  int ii = (i < M) ? i : 0;
  const float* p = canvas + (size_t)(b*NMAX + off + ii)*3;
  float p0 = p[0], p1 = p[1], p2 = p[2];
  float f1[64];
#pragma unroll
  for (int j=0;j<64;j++)
    f1[j] = fmaxf(0.f, b1[j] + p0*w1[j] + p1*w1[64+j] + p2*w1[128+j]);
  float a[16];
  const float* b2p = b2 + jc*16;
#pragma unroll
  for (int j=0;j<16;j++) a[j] = b2p[j];
#pragma unroll
  for (int k=0;k<64;k++){
    const float* wr = w2 + k*128 + jc*16;   /* wave-uniform -> scalar */
#pragma unroll
    for (int j=0;j<16;j++) a[j] = fmaf(f1[k], wr[j], a[j]);
  }
  if (i < M){
    int base = b*N0 + i;
#pragma unroll
    for (int j=0;j<16;j++)
      f2buf[(size_t)(jc*16 + j)*F2S + base] = fmaxf(a[j], 0.f);
  }
}

/* ---------- enc layer 3 + running max-pool ---------- */
__global__ __launch_bounds__(256) void enc3_kernel(
    const float* __restrict__ f2buf, const float* __restrict__ w3,
    const float* __restrict__ b3, unsigned* __restrict__ gmax, int M)
{
  int b = blockIdx.y;
  int dc = blockIdx.z;            /* 0..15 */
  int i = blockIdx.x*256 + threadIdx.x;
  bool act = i < M;
  int ii = act ? i : 0;
  const float* fp = f2buf + b*N0 + ii;
  float a[16];
  const float* b3p = b3 + dc*16;
#pragma unroll
  for (int d=0;d<16;d++) a[d] = b3p[d];
  for (int k=0;k<128;k++){
    float fk = fp[(size_t)k*F2S];           /* coalesced */
    const float* wr = w3 + k*256 + dc*16;   /* wave-uniform -> scalar */
#pragma unroll
    for (int d=0;d<16;d++) a[d] = fmaf(fk, wr[d], a[d]);
  }
#pragma unroll
  for (int d=0;d<16;d++){
    float v = act ? a[d] : -3.4e38f;
#pragma unroll
    for (int s=32;s>0;s>>=1) v = fmaxf(v, __shfl_down(v, s, 64));
    if ((threadIdx.x & 63) == 0) atomicMax(&gmax[b*GD + dc*16 + d], enc_f(v));
  }
}

/* ---------- scores partials + lstm partials, one dispatch ---------- */
__global__ __launch_bounds__(512) void sl_kernel(
    const float* __restrict__ canvas, const float* __restrict__ aw1,
    const float* __restrict__ ab1, const float* __restrict__ aw2,
    const float* __restrict__ ab2, const unsigned* __restrict__ gmax,
    const float* __restrict__ h_in,
    const float* __restrict__ wih, const float* __restrict__ whh,
    float* __restrict__ part, float* __restrict__ gpart, int N, int nch)
{
  __shared__ float sBatt[128];
  __shared__ float red[16];
  __shared__ float sV[BB][12];
  int blk = blockIdx.x;
  int tid = threadIdx.x;
  if (blk < 4*nch){
    int b = blk / nch, ch = blk - b*nch;
    if (tid < 128){
      float a = ab1[tid];
      for (int k=0;k<GD;k++) a += dec_f(gmax[b*GD+k]) * aw1[(3+k)*128 + tid];
      for (int k=0;k<HD;k++) a += h_in[b*HD+k] * aw1[(3+GD+k)*128 + tid];
      sBatt[tid] = a;
    }
    __syncthreads();
    int i = ch*512 + tid;
    bool act = i < N;
    float p0=0.f,p1=0.f,p2=0.f,s=-3.4e38f;
    if (act){
      const float* pp = canvas + (size_t)(b*NMAX + i)*3;
      p0=pp[0]; p1=pp[1]; p2=pp[2];
      s = ab2[0];
      for (int j=0;j<128;j++){
        float v = sBatt[j] + p0*aw1[j] + p1*aw1[128+j] + p2*aw1[256+j];
        s += fmaxf(v, 0.f)*aw2[j];
      }
    }
    float mb = block_max(s, red);
    float e = act ? expf(s - mb) : 0.f;
    float se = block_sum(e, red);
    float wx = block_sum(e*p0, red);
    float wy = block_sum(e*p1, red);
    float wz = block_sum(e*p2, red);
    if (tid==0){
      float* pr = part + (size_t)(b*32 + ch)*8;
      pr[0]=mb; pr[1]=se; pr[2]=wx; pr[3]=wy; pr[4]=wz;
    }
  } else {
    int cc = blk - 4*nch;   /* 0..31 */
    if (tid < BB*12){
      int b = tid/12, j = tid - b*12;
      int r = cc*12 + j;
      sV[b][j] = (r < 256) ? dec_f(gmax[b*GD + r]) : h_in[b*HD + (r-256)];
    }
    __syncthreads();
    float a0=0.f,a1=0.f,a2=0.f,a3=0.f;
#pragma unroll
    for (int j=0;j<12;j++){
      int r = cc*12 + j;
      const float* wr = (r < 256) ? (wih + (size_t)r*512) : (whh + (size_t)(r-256)*512);
      float wvv = wr[tid];
      a0 += sV[0][j]*wvv; a1 += sV[1][j]*wvv;
      a2 += sV[2][j]*wvv; a3 += sV[3][j]*wvv;
    }
    float* gp = gpart + (size_t)cc*(BB*512);
    gp[0*512+tid]=a0; gp[1*512+tid]=a1; gp[2*512+tid]=a2; gp[3*512+tid]=a3;
  }
}

/* ---------- stepA: center + top-64 threshold + patch mean.
   Templated on Q = per-thread register tile count (N <= Q*1024). ---------- */
template<int Q>
__global__ __launch_bounds__(1024) void stepA_kernel(
    const float* __restrict__ canvas, const float* __restrict__ part,
    float* __restrict__ centerpf, int N, int nch)
{
  __shared__ float red[16];
  __shared__ float sC[3];
  __shared__ unsigned cbufA[2][16];
  __shared__ unsigned cbufB[2][16];
  __shared__ int tieCnt;
  __shared__ int tieIdx[256];

  int b = blockIdx.x;
  int tid = threadIdx.x;
  int lane = tid & 63, wid = tid >> 6;
  const float* cv = canvas + (size_t)b*NMAX*3;

  float pm=-3.4e38f, pse=0.f, pwx=0.f, pwy=0.f, pwz=0.f;
  if (tid < nch){
    const float* pp = part + (size_t)(b*32 + tid)*8;
    pm=pp[0]; pse=pp[1]; pwx=pp[2]; pwy=pp[3]; pwz=pp[4];
  }
  float M = block_max(pm, red);
  float w = (tid < nch) ? expf(pm - M) : 0.f;
  float se = block_sum(pse*w, red);
  float wx = block_sum(pwx*w, red);
  float wy = block_sum(pwy*w, red);
  float wz = block_sum(pwz*w, red);
  if (tid==0){ sC[0]=wx/se; sC[1]=wy/se; sC[2]=wz/se; }
  __syncthreads();
  float cx=sC[0], cy=sC[1], cz=sC[2];
  if (tid<3) centerpf[b*3+tid] = sC[tid];

  unsigned ur[Q];
#pragma unroll
  for (int q=0;q<Q;q++){
    ur[q] = 0xFFFFFFFFu;
    int i = tid + q*1024;
    if (i < N){
      const float* p = cv + (size_t)i*3;
      float dx=p[0]-cx, dy=p[1]-cy, dz=p[2]-cz;
      ur[q] = __float_as_uint(dx*dx + dy*dy + dz*dz);
    }
  }

  unsigned T = 0u;
  int cntBelow = 0;
  int par = 0;
  {
    unsigned cand = 1u<<30;
    unsigned tc = 0;
#pragma unroll
    for (int q=0;q<Q;q++) tc += (ur[q] < cand) ? 1u : 0u;
#pragma unroll
    for (int s=32;s>0;s>>=1) tc += __shfl_down(tc, s, 64);
    if (lane==0) cbufA[par][wid] = tc;
    __syncthreads();
    unsigned tot = 0;
#pragma unroll
    for (int i2=0;i2<16;i2++) tot += cbufA[par][i2];
    if ((int)tot < KSEL){ T = cand; cntBelow = (int)tot; }
    par ^= 1;
  }
  for (int bit=29; bit>=1; bit-=2){
    unsigned q1 = 1u<<(bit-1);
    unsigned c1 = T + q1, c2 = T + 2u*q1, c3 = T + 3u*q1;
    unsigned ta = 0, tb = 0;
#pragma unroll
    for (int q=0;q<Q;q++){
      unsigned u = ur[q];
      ta += (u < c1 ? 1u : 0u) | (u < c2 ? 0x10000u : 0u);
      tb += (u < c3 ? 1u : 0u);
    }
#pragma unroll
    for (int s=32;s>0;s>>=1){ ta += __shfl_down(ta, s, 64); tb += __shfl_down(tb, s, 64); }
    if (lane==0){ cbufA[par][wid] = ta; cbufB[par][wid] = tb; }
    __syncthreads();
    unsigned sa = 0, sb = 0;
#pragma unroll
    for (int i2=0;i2<16;i2++){ sa += cbufA[par][i2]; sb += cbufB[par][i2]; }
    int n1 = (int)(sa & 0xFFFFu), n2 = (int)(sa >> 16), n3 = (int)sb;
    if (n3 < KSEL){ T = c3; cntBelow = n3; }
    else if (n2 < KSEL){ T = c2; cntBelow = n2; }
    else if (n1 < KSEL){ T = c1; cntBelow = n1; }
    par ^= 1;
  }
  int kneed = KSEL - cntBelow;

  if (tid==0) tieCnt = 0;
  __syncthreads();
  float sx=0.f, sy=0.f, sz=0.f;
#pragma unroll
  for (int q=0;q<Q;q++){
    unsigned u = ur[q];
    if (u < T){
      const float* p = cv + (size_t)(tid + q*1024)*3;
      sx += p[0]; sy += p[1]; sz += p[2];
    } else if (u == T){
      int pos = atomicAdd(&tieCnt, 1);
      if (pos < 256) tieIdx[pos] = tid + q*1024;
    }
  }
  __syncthreads();
  sx = block_sum(sx, red);
  sy = block_sum(sy, red);
  sz = block_sum(sz, red);
  if (tid==0){
    int mm = tieCnt < 256 ? tieCnt : 256;
    for (int t=0;t<kneed;t++){
      int best=-1, bi=0x7fffffff;
      for (int q=0;q<mm;q++){ int v = tieIdx[q]; if (v < bi){ bi=v; best=q; } }
      if (best >= 0){
        tieIdx[best] = 0x7fffffff;
        const float* p = cv + (size_t)bi*3;
        sx += p[0]; sy += p[1]; sz += p[2];
      }
    }
    centerpf[16 + b*3 + 0] = sx/KSEL - cx;
    centerpf[16 + b*3 + 1] = sy/KSEL - cy;
    centerpf[16 + b*3 + 2] = sz/KSEL - cz;
  }
}

/* ---------- refenc12: LSTM finish + decoder + canvas append + enc12, all in
   enc12's grid shape (5, BB, 8) = 160 blocks, 256 pts/block (weight-stream
   spread preserved — r11's mistake avoided). Each thread decodes its OWN
   point (3x128 MACs vs L2-hot rw2), so no cross-block dependency. ---------- */
__global__ __launch_bounds__(256) void refenc12_kernel(
    float* __restrict__ canvas, const float* __restrict__ gpart,
    const float* __restrict__ centerpf,
    const float* __restrict__ c_in, float* __restrict__ c_out,
    float* __restrict__ h_out,
    const float* __restrict__ wih,
    const float* __restrict__ bih, const float* __restrict__ bhh,
    const float* __restrict__ rw1, const float* __restrict__ rb1,
    const float* __restrict__ rw2, const float* __restrict__ rb2,
    const float* __restrict__ w1, const float* __restrict__ b1,
    const float* __restrict__ w2, const float* __restrict__ b2,
    float* __restrict__ f2buf, int N)
{
  __shared__ float sG[512];
  __shared__ float sH[HD];
  __shared__ float sRf[HD];
  int b = blockIdx.y;
  int jc = blockIdx.z;            /* 0..7: 16-feature chunk of f2 */
  int tid = threadIdx.x;
  float cx = centerpf[b*3+0], cy = centerpf[b*3+1], cz = centerpf[b*3+2];
  float fx = centerpf[16+b*3+0], fy = centerpf[16+b*3+1], fz = centerpf[16+b*3+2];
  /* LSTM gate finish (redundant per block; gpart is L2-hot) */
#pragma unroll
  for (int half=0; half<2; half++){
    int o = tid + half*256;
    float gg = bih[o] + bhh[o];
    for (int cc=0; cc<32; cc++) gg += gpart[(size_t)cc*(BB*512) + b*512 + o];
    gg += cx*wih[(size_t)256*512+o] + cy*wih[(size_t)257*512+o] + cz*wih[(size_t)258*512+o];
    gg += fx*wih[(size_t)259*512+o] + fy*wih[(size_t)260*512+o] + fz*wih[(size_t)261*512+o];
    sG[o] = gg;
  }
  __syncthreads();
  if (tid < HD){
    float gi=sG[tid], gf=sG[128+tid], gg2=sG[256+tid], go=sG[384+tid];
    float cn = sigm(gf)*c_in[b*HD+tid] + sigm(gi)*tanhf(gg2);
    float hn = sigm(go)*tanhf(cn);
    sH[tid] = hn;
    if (blockIdx.x==0 && jc==0){ c_out[b*HD+tid]=cn; h_out[b*HD+tid]=hn; }
  }
  __syncthreads();
  if (tid < HD){
    float a = rb1[tid];
    for (int k=0;k<HD;k++) a += sH[k]*rw1[k*HD + tid];
    sRf[tid] = fmaxf(a, 0.f);
  }
  __syncthreads();
  /* per-thread decode of own point */
  int i = blockIdx.x*256 + tid;
  bool act = i < NEWP;
  int ic = act ? i : 0;
  float a0 = rb2[3*ic], a1 = rb2[3*ic+1], a2 = rb2[3*ic+2];
  for (int k=0;k<HD;k++){
    const float* wv = rw2 + (size_t)k*(NEWP*3) + 3*ic;
    float hk = sRf[k];
    a0 = fmaf(hk, wv[0], a0); a1 = fmaf(hk, wv[1], a1); a2 = fmaf(hk, wv[2], a2);
  }
  float p0 = fmaf(a0, 0.02f, cx), p1 = fmaf(a1, 0.02f, cy), p2 = fmaf(a2, 0.02f, cz);
  if (act && jc==0){
    float* cp = canvas + ((size_t)b*NMAX + N + i)*3;
    cp[0]=p0; cp[1]=p1; cp[2]=p2;
  }
  /* enc12 of the decoded point: f1 in regs, chunk jc of f2 */
  float f1[64];
#pragma unroll
  for (int j=0;j<64;j++)
    f1[j] = fmaxf(0.f, b1[j] + p0*w1[j] + p1*w1[64+j] + p2*w1[128+j]);
  float a[16];
  const float* b2p = b2 + jc*16;
#pragma unroll
  for (int j=0;j<16;j++) a[j] = b2p[j];
#pragma unroll
  for (int k=0;k<64;k++){
    const float* wr = w2 + k*128 + jc*16;   /* wave-uniform -> scalar */
#pragma unroll
    for (int j=0;j<16;j++) a[j] = fmaf(f1[k], wr[j], a[j]);
  }
  if (act){
    int base = b*N0 + i;
#pragma unroll
    for (int j=0;j<16;j++)
      f2buf[(size_t)(jc*16 + j)*F2S + base] = fmaxf(a[j], 0.f);
  }
}

/* ---------- chamfer (4 VALU/pair, at its measured roofline) ---------- */
__global__ __launch_bounds__(512) void chamfer_kernel(
    const float* __restrict__ canvas, const float* __restrict__ gt,
    unsigned* __restrict__ minAB, unsigned* __restrict__ minCD)
{
  __shared__ float sy0[1024], sy1[1024], sy2[1024], sny[1024];
  int id = blockIdx.x;
  int dir, rem;
  if (id < 32){ dir=0; rem=id; }
  else if (id < 64){ dir=1; rem=id-32; }
  else if (id < 160){ dir=2; rem=id-64; }
  else { dir=3; rem=id-160; }
  int b, xb, yb;
  if (dir < 2){ b = rem>>3; int l = rem&7; xb = l>>2; yb = l&3; }
  else if (dir == 2){ b = rem/24; int l = rem%24; xb = l>>2; yb = l&3; }
  else { b = rem/24; int l = rem%24; xb = l/12; yb = l%12; }

  int Nx, Ny; const float* X; const float* Y; unsigned* mp;
  if (dir==0){      Nx=N0;   Ny=N0;   X=canvas+(size_t)b*NMAX*3;       Y=gt+(size_t)b*N0*3;            mp=minAB + b*N0; }
  else if (dir==1){ Nx=N0;   Ny=N0;   X=gt+(size_t)b*N0*3;             Y=canvas+(size_t)b*NMAX*3;      mp=minAB + BB*N0 + b*N0; }
  else if (dir==2){ Nx=NNEW; Ny=N0;   X=canvas+((size_t)b*NMAX+N0)*3;  Y=gt+(size_t)b*N0*3;            mp=minCD + b*NNEW; }
  else {            Nx=N0;   Ny=NNEW; X=gt+(size_t)b*N0*3;             Y=canvas+((size_t)b*NMAX+N0)*3; mp=minCD + BB*NNEW + b*N0; }

  int xbase = xb*2048;
  int ybase = yb*1024;
  int tn = min(1024, Ny - ybase);
  int tid = threadIdx.x;
  for (int t=tid; t<tn; t+=512){
    const float* yp = Y + (size_t)(ybase+t)*3;
    float y0=yp[0], y1=yp[1], y2=yp[2];
    sy0[t]=-2.f*y0; sy1[t]=-2.f*y1; sy2[t]=-2.f*y2; sny[t]=y0*y0+y1*y1+y2*y2;
  }
  __syncthreads();

  float X0[4],X1[4],X2[4],NXr[4],MN[4]; int XI[4]; bool VA[4];
#pragma unroll
  for (int q=0;q<4;q++){
    int x = xbase + q*512 + tid;
    VA[q] = x < Nx;
    int xc = VA[q] ? x : 0;
    const float* xp = X + (size_t)xc*3;
    X0[q]=xp[0]; X1[q]=xp[1]; X2[q]=xp[2];
    NXr[q] = X0[q]*X0[q] + X1[q]*X1[q] + X2[q]*X2[q];
    MN[q] = 3.4e38f; XI[q] = xc;
  }
  const float4* v0 = (const float4*)sy0;
  const float4* v1 = (const float4*)sy1;
  const float4* v2 = (const float4*)sy2;
  const float4* vn = (const float4*)sny;
  int j4n = tn >> 2;
  for (int j=0;j<j4n;j++){
    float4 a0 = v0[j], a1 = v1[j], a2 = v2[j], an = vn[j];
#pragma unroll
    for (int e=0;e<4;e++){
      float y0 = ((const float*)&a0)[e];
      float y1 = ((const float*)&a1)[e];
      float y2 = ((const float*)&a2)[e];
      float ny = ((const float*)&an)[e];
#pragma unroll
      for (int q=0;q<4;q++){
        float d = fmaf(X0[q], y0, fmaf(X1[q], y1, fmaf(X2[q], y2, ny)));
        MN[q] = fminf(MN[q], d);
      }
    }
  }
  for (int j=j4n*4; j<tn; j++){
    float y0=sy0[j], y1=sy1[j], y2=sy2[j], ny=sny[j];
#pragma unroll
    for (int q=0;q<4;q++){
      float d = fmaf(X0[q], y0, fmaf(X1[q], y1, fmaf(X2[q], y2, ny)));
      MN[q] = fminf(MN[q], d);
    }
  }
#pragma unroll
  for (int q=0;q<4;q++)
    if (VA[q]) atomicMin(&mp[XI[q]], enc_f(MN[q] + NXr[q]));
}

__global__ __launch_bounds__(256) void chamfer_reduce_kernel(
    const unsigned* __restrict__ minAB, const unsigned* __restrict__ minCD,
    float* __restrict__ acc)
{
  __shared__ float red[16];
  int s = blockIdx.x, dir = s>>2, b = s&3;
  const unsigned* mp; int len;
  if (dir==0){      mp=minAB + b*N0;            len=N0; }
  else if (dir==1){ mp=minAB + BB*N0 + b*N0;    len=N0; }
  else if (dir==2){ mp=minCD + b*NNEW;          len=NNEW; }
  else {            mp=minCD + BB*NNEW + b*N0;  len=N0; }
  float v = 0.f;
  for (int i=threadIdx.x;i<len;i+=256) v += dec_f(mp[i]);
  v = block_sum(v, red);
  if (threadIdx.x==0) acc[s] = v;
}

__global__ void finish_kernel(const float* __restrict__ acc, float* __restrict__ out)
{
  if (threadIdx.x == 0 && blockIdx.x == 0){
    float cd1 = 0.f, cd2 = 0.f;
    for (int b=0;b<BB;b++) cd1 += acc[b]/(float)N0 + acc[4+b]/(float)N0;
    for (int b=0;b<BB;b++) cd2 += acc[8+b]/(float)NNEW + acc[12+b]/(float)N0;
    out[0] = 0.1f*(cd1/BB) + 1.0f*(cd2/BB);
  }
}

extern "C" void kernel_launch(void* const* d_in, const int* in_sizes, int n_in,
                              void* d_out, int out_size, void* d_ws, size_t ws_size,
                              hipStream_t stream) {
  (void)in_sizes; (void)n_in; (void)out_size; (void)ws_size;
  const float* points   = (const float*)d_in[0];
  const float* gt       = (const float*)d_in[1];
  const float* enc_w1   = (const float*)d_in[2];
  const float* enc_b1   = (const float*)d_in[3];
  const float* enc_w2   = (const float*)d_in[4];
  const float* enc_b2   = (const float*)d_in[5];
  const float* enc_w3   = (const float*)d_in[6];
  const float* enc_b3   = (const float*)d_in[7];
  const float* att_w1   = (const float*)d_in[8];
  const float* att_b1   = (const float*)d_in[9];
  const float* att_w2   = (const float*)d_in[10];
  const float* att_b2   = (const float*)d_in[11];
  const float* lstm_wih = (const float*)d_in[12];
  const float* lstm_whh = (const float*)d_in[13];
  const float* lstm_bih = (const float*)d_in[14];
  const float* lstm_bhh = (const float*)d_in[15];
  const float* ref_w1   = (const float*)d_in[16];
  const float* ref_b1   = (const float*)d_in[17];
  const float* ref_w2   = (const float*)d_in[18];
  const float* ref_b2   = (const float*)d_in[19];
  float* out = (float*)d_out;

  float* ws       = (float*)d_ws;
  float* canvas   = ws + OFF_CANVAS;
  unsigned* minAB = (unsigned*)(ws + OFF_MINAB);
  unsigned* minCD = (unsigned*)(ws + OFF_MINCD);
  unsigned* gmaxp = (unsigned*)(ws + OFF_GMAX);
  float* hb       = ws + OFF_H;
  float* cb       = ws + OFF_C;
  float* acc      = ws + OFF_ACC;
  float* centerb  = ws + OFF_CENTER;
  float* partb    = ws + OFF_PART;
  float* gpartb   = ws + OFF_GPART;
  float* f2buf    = ws + OFF_F2;

  init_kernel<<<dim3(128), 512, 0, stream>>>(points, canvas, minAB, minCD, gmaxp, hb, cb);
  enc12_kernel<<<dim3(16, BB, 8), 256, 0, stream>>>(canvas, enc_w1, enc_b1, enc_w2, enc_b2, f2buf, 0, N0);
  enc3_kernel<<<dim3(16, BB, 16), 256, 0, stream>>>(f2buf, enc_w3, enc_b3, gmaxp, N0);

  for (int t=0; t<NSTEPS; t++){
    int N   = N0 + t*NEWP;
    int nch = (N + 511) >> 9;
    float* h_in  = hb + (t&1)*BB*HD;
    float* h_out = hb + ((t+1)&1)*BB*HD;
    float* c_in  = cb + (t&1)*BB*HD;
    float* c_out = cb + ((t+1)&1)*BB*HD;
    sl_kernel<<<dim3(4*nch + 32), 512, 0, stream>>>(canvas, att_w1, att_b1, att_w2, att_b2,
                                                    gmaxp, h_in, lstm_wih, lstm_whh,
                                                    partb, gpartb, N, nch);
    if      (N <= 4096)  stepA_kernel<4> <<<dim3(BB), 1024, 0, stream>>>(canvas, partb, centerb, N, nch);
    else if (N <= 8192)  stepA_kernel<8> <<<dim3(BB), 1024, 0, stream>>>(canvas, partb, centerb, N, nch);
    else if (N <= 12288) stepA_kernel<12><<<dim3(BB), 1024, 0, stream>>>(canvas, partb, centerb, N, nch);
    else                 stepA_kernel<16><<<dim3(BB), 1024, 0, stream>>>(canvas, partb, centerb, N, nch);
    refenc12_kernel<<<dim3(5, BB, 8), 256, 0, stream>>>(canvas, gpartb, centerb,
                                                        c_in, c_out, h_out,
                                                        lstm_wih, lstm_bih, lstm_bhh,
                                                        ref_w1, ref_b1, ref_w2, ref_b2,
                                                        enc_w1, enc_b1, enc_w2, enc_b2,
                                                        f2buf, N);
    if (t < NSTEPS-1){
      enc3_kernel<<<dim3(5, BB, 16), 256, 0, stream>>>(f2buf, enc_w3, enc_b3, gmaxp, NEWP);
    }
  }

  chamfer_kernel<<<dim3(256), 512, 0, stream>>>(canvas, gt, minAB, minCD);
  chamfer_reduce_kernel<<<dim3(16), 256, 0, stream>>>(minAB, minCD, acc);
  finish_kernel<<<1, 64, 0, stream>>>(acc, out);
}